// Round 5
// baseline (1466.527 us; speedup 1.0000x reference)
//
#include <hip/hip_runtime.h>
#include <cmath>
#include <climits>

#define TK 16
#define TDIM 64
#define LDT 68

// Generic-stride f32 GEMM: C[m,n] = sum_k A(m,k)*B(k,n) (+ addmat / + bias,relu)
// A(m,k) = A[m*sAm + k*sAk], B(k,n) = B[k*sBk + n*sBn]. All dims multiples of 64/16.
__global__ __launch_bounds__(256)
void gemm_f32(const float* __restrict__ A, const float* __restrict__ B,
              float* __restrict__ C, int M, int N, int K,
              int sAm, int sAk, int sBk, int sBn, int ldc,
              const float* __restrict__ addmat, int ldadd,
              const float* __restrict__ bias, int do_relu)
{
    __shared__ float As[TK][LDT];
    __shared__ float Bs[TK][LDT];
    const int t  = threadIdx.x;
    const int tx = t & 15, ty = t >> 4;
    const int m0 = blockIdx.x * TDIM, n0 = blockIdx.y * TDIM;
    float acc[4][4] = {};
    for (int k0 = 0; k0 < K; k0 += TK) {
        if (sAk == 1) {
#pragma unroll
            for (int i = 0; i < 4; ++i) {
                int idx = t + i * 256; int kk = idx & 15, mm = idx >> 4;
                As[kk][mm] = A[(size_t)(m0 + mm) * sAm + (size_t)(k0 + kk)];
            }
        } else {
#pragma unroll
            for (int i = 0; i < 4; ++i) {
                int idx = t + i * 256; int mm = idx & 63, kk = idx >> 6;
                As[kk][mm] = A[(size_t)(m0 + mm) * sAm + (size_t)(k0 + kk) * sAk];
            }
        }
        if (sBn == 1) {
#pragma unroll
            for (int i = 0; i < 4; ++i) {
                int idx = t + i * 256; int nn = idx & 63, kk = idx >> 6;
                Bs[kk][nn] = B[(size_t)(k0 + kk) * sBk + (size_t)(n0 + nn)];
            }
        } else {
#pragma unroll
            for (int i = 0; i < 4; ++i) {
                int idx = t + i * 256; int kk = idx & 15, nn = idx >> 4;
                Bs[kk][nn] = B[(size_t)(k0 + kk) * sBk + (size_t)(n0 + nn) * sBn];
            }
        }
        __syncthreads();
#pragma unroll
        for (int kk = 0; kk < TK; ++kk) {
            float a[4], b[4];
#pragma unroll
            for (int i = 0; i < 4; ++i) a[i] = As[kk][ty * 4 + i];
#pragma unroll
            for (int j = 0; j < 4; ++j) b[j] = Bs[kk][tx * 4 + j];
#pragma unroll
            for (int i = 0; i < 4; ++i)
#pragma unroll
                for (int j = 0; j < 4; ++j)
                    acc[i][j] += a[i] * b[j];
        }
        __syncthreads();
    }
#pragma unroll
    for (int i = 0; i < 4; ++i) {
        int row = m0 + ty * 4 + i;
#pragma unroll
        for (int j = 0; j < 4; ++j) {
            int col = n0 + tx * 4 + j;
            float v = acc[i][j];
            if (addmat) v += addmat[(size_t)row * ldadd + col];
            if (bias)   v += bias[col];
            if (do_relu) v = fmaxf(v, 0.f);
            C[(size_t)row * ldc + col] = v;
        }
    }
}

// ne[i] = sum_d U[d*Ncol + i]^2  (column squared norms, coalesced across i)
__global__ void colsq_kernel(const float* __restrict__ U, float* __restrict__ out,
                             int D, int Ncol)
{
    int i = blockIdx.x * blockDim.x + threadIdx.x;
    if (i >= Ncol) return;
    float s = 0.f;
    for (int d = 0; d < D; ++d) { float v = U[(size_t)d * Ncol + i]; s += v * v; }
    out[i] = s;
}

// l[i] = sqrt(ne[i]) / sqrt(sum_d m[i,d]^2); one wave per row
__global__ void lscale_kernel(const float* __restrict__ m, const float* __restrict__ ne,
                              float* __restrict__ l, int rows, int D)
{
    int gid  = blockIdx.x * blockDim.x + threadIdx.x;
    int wave = gid >> 6;
    int lane = gid & 63;
    if (wave >= rows) return;
    const float* r = m + (size_t)wave * D;
    float s = 0.f;
    for (int d = lane; d < D; d += 64) { float v = r[d]; s += v * v; }
#pragma unroll
    for (int off = 32; off; off >>= 1) s += __shfl_down(s, off);
    if (lane == 0) l[wave] = sqrtf(ne[wave]) / sqrtf(s);
}

// f[i*D+d] = U[d*Ncol+i] + l[i]*m[i*D+d]
__global__ void fbuild_kernel(const float* __restrict__ U, const float* __restrict__ m,
                              const float* __restrict__ l, float* __restrict__ f,
                              int rows, int D, int Ncol)
{
    int idx = blockIdx.x * blockDim.x + threadIdx.x;
    if (idx >= rows * D) return;
    int i = idx / D, d = idx - i * D;
    f[idx] = U[(size_t)d * Ncol + i] + l[i] * m[idx];
}

// row-wise L2 normalize in place: e /= max(||e||, 1e-12); one wave per row
__global__ void normrows_kernel(float* __restrict__ E, int rows, int D)
{
    int gid  = blockIdx.x * blockDim.x + threadIdx.x;
    int wave = gid >> 6;
    int lane = gid & 63;
    if (wave >= rows) return;
    float* r = E + (size_t)wave * D;
    float s = 0.f;
    for (int d = lane; d < D; d += 64) { float v = r[d]; s += v * v; }
#pragma unroll
    for (int off = 32; off; off >>= 1) s += __shfl_xor(s, off);
    float denom = fmaxf(sqrtf(s), 1e-12f);
    for (int d = lane; d < D; d += 64) r[d] = r[d] / denom;
}

// per row a of sim (A x A): dd = (2-2*s)^2 ; rowmax(dd), stable top-2 (value,index)
__global__ __launch_bounds__(256)
void rowscan_kernel(const float* __restrict__ sim, float* __restrict__ rowmax,
                    int* __restrict__ n0, int* __restrict__ n1, int A)
{
    int a = blockIdx.x;
    const float* row = sim + (size_t)a * A;
    int tid = threadIdx.x;
    float vmax = -1e30f;
    float b0v = 1e30f, b1v = 1e30f;
    int   b0i = INT_MAX, b1i = INT_MAX;
    for (int j = tid; j < A; j += 256) {
        float s  = row[j];
        float tt = 2.f - 2.f * s;
        float dd = tt * tt;
        vmax = fmaxf(vmax, dd);
        if (dd < b0v) { b1v = b0v; b1i = b0i; b0v = dd; b0i = j; }
        else if (dd < b1v) { b1v = dd; b1i = j; }
        // j strictly increasing within thread -> stable (earliest index wins ties)
    }
    __shared__ float s_max[256], s_v0[256], s_v1[256];
    __shared__ int   s_i0[256], s_i1[256];
    s_max[tid] = vmax; s_v0[tid] = b0v; s_i0[tid] = b0i; s_v1[tid] = b1v; s_i1[tid] = b1i;
    __syncthreads();
    for (int off = 128; off; off >>= 1) {
        if (tid < off) {
            s_max[tid] = fmaxf(s_max[tid], s_max[tid + off]);
            float a0v = s_v0[tid], a1v = s_v1[tid];
            int   a0i = s_i0[tid], a1i = s_i1[tid];
            float c0v = s_v0[tid + off], c1v = s_v1[tid + off];
            int   c0i = s_i0[tid + off], c1i = s_i1[tid + off];
            float r0v, r1v; int r0i, r1i;
            bool c0_lt_a0 = (c0v < a0v) || (c0v == a0v && c0i < a0i);
            if (c0_lt_a0) {
                r0v = c0v; r0i = c0i;
                bool a0_lt_c1 = (a0v < c1v) || (a0v == c1v && a0i < c1i);
                if (a0_lt_c1) { r1v = a0v; r1i = a0i; } else { r1v = c1v; r1i = c1i; }
            } else {
                r0v = a0v; r0i = a0i;
                bool c0_lt_a1 = (c0v < a1v) || (c0v == a1v && c0i < a1i);
                if (c0_lt_a1) { r1v = c0v; r1i = c0i; } else { r1v = a1v; r1i = a1i; }
            }
            s_v0[tid] = r0v; s_i0[tid] = r0i; s_v1[tid] = r1v; s_i1[tid] = r1i;
        }
        __syncthreads();
    }
    if (tid == 0) { rowmax[a] = s_max[0]; n0[a] = s_i0[0]; n1[a] = s_i1[0]; }
}

// per-row k-reciprocal expansion set (k1=1): idx4, vals
__global__ void setbuild_kernel(const float* __restrict__ sim, const float* __restrict__ rmx,
                                const int* __restrict__ n0, const int* __restrict__ n1,
                                int* __restrict__ idx4, float* __restrict__ vals, int A)
{
    int a = blockIdx.x * blockDim.x + threadIdx.x;
    if (a >= A) return;
    int c0 = n0[a], c1 = n1[a];
    bool v0 = (n0[c0] == a) || (n1[c0] == a);
    bool v1 = (n0[c1] == a) || (n1[c1] == a);
    int e0 = n0[c0], e1 = n0[c1];
    bool inR_e0 = (v0 && e0 == c0) || (v1 && e0 == c1);
    bool inR_e1 = (v0 && e1 == c0) || (v1 && e1 == c1);
    bool v2 = v0 && (n0[e0] == c0) && inR_e0;
    bool v3 = v1 && (n0[e1] == c1) && inR_e1;
    int  id[4]  = { c0, c1, e0, e1 };
    bool raw[4] = { v0, v1, v2, v3 };
    bool kept[4];
    kept[0] = raw[0];
#pragma unroll
    for (int j = 1; j < 4; ++j) {
        bool dup = false;
        for (int k = 0; k < j; ++k) dup = dup || (kept[k] && id[k] == id[j]);
        kept[j] = raw[j] && !dup;
    }
    float rm = rmx[a];
    const float* row = sim + (size_t)a * A;
    float w[4]; float wsum = 0.f;
#pragma unroll
    for (int k = 0; k < 4; ++k) {
        float s  = row[id[k]];
        float tt = 2.f - 2.f * s;
        float dd = tt * tt / rm;
        w[k] = kept[k] ? expf(-dd) : 0.f;
        wsum += w[k];
    }
    float den = (wsum > 0.f) ? wsum : 1.f;
#pragma unroll
    for (int k = 0; k < 4; ++k) {
        idx4[a * 4 + k] = id[k];
        vals[a * 4 + k] = w[k] / den;
    }
}

// outputs: Mp_before, Mp = 1 - (0.7*jac + 0.3*d), thr_flag
__global__ __launch_bounds__(256)
void final_kernel(const float* __restrict__ sim, const float* __restrict__ rmx,
                  const int* __restrict__ idx4, const float* __restrict__ vals,
                  const float* __restrict__ iou, const float* __restrict__ kf,
                  const float* __restrict__ thr, float* __restrict__ out,
                  int Q, int G, int A)
{
    int j = blockIdx.x * 16 + threadIdx.x;
    int i = blockIdx.y * 16 + threadIdx.y;
    if (i >= Q || j >= G) return;
    int b = Q + j;
    float s = sim[(size_t)i * A + b];   // Mp_before[i][j]
    int   ia[4], ib[4];
    float va[4], vb[4];
#pragma unroll
    for (int k = 0; k < 4; ++k) {
        ia[k] = idx4[i * 4 + k]; va[k] = vals[i * 4 + k];
        ib[k] = idx4[b * 4 + k]; vb[k] = vals[b * 4 + k];
    }
    float t = 0.f;
#pragma unroll
    for (int k = 0; k < 4; ++k) {
        float sm = 0.f;
#pragma unroll
        for (int m = 0; m < 4; ++m) sm += (ib[m] == ia[k]) ? vb[m] : 0.f;
        t += fminf(va[k], sm);
    }
    float jac = 1.f - t / (2.f - t);
    float tt  = 2.f - 2.f * s;
    float dqg = tt * tt / rmx[i];
    float fin = jac * 0.7f + dqg * 0.3f;
    size_t o  = (size_t)i * G + j;
    size_t QG = (size_t)Q * G;
    out[o]          = s;
    out[QG + o]     = 1.f - fin;
    float iv = iou[o], kv = kf[o];
    out[2 * QG + o] = (kv == -1.f || iv == 0.f || s < thr[0]) ? 1.f : 0.f;
}

extern "C" void kernel_launch(void* const* d_in, const int* in_sizes, int n_in,
                              void* d_out, int out_size, void* d_ws, size_t ws_size,
                              hipStream_t stream)
{
    const float* Us   = (const float*)d_in[0];  // (512, 2048)
    const float* Ut   = (const float*)d_in[1];  // (512, 2048)
    const float* iou  = (const float*)d_in[2];  // (2048, 2048)
    const float* kf   = (const float*)d_in[3];  // (2048, 2048)
    const float* thr  = (const float*)d_in[4];  // (1,)
    const float* W    = (const float*)d_in[5];  // (512, 512)
    const float* bias = (const float*)d_in[6];  // (512,)
    float* out = (float*)d_out;

    const int Q = 2048, G = 2048, D = 512, A = 4096;
    const size_t M1 = 1024 * 1024;

    float* ws  = (float*)d_ws;
    // Aliased layout (peak ~72.5 MB):
    float* sim = ws;             // 16M floats; written at G6 (early bufs dead by then)
    float* E   = ws + 16 * M1;   // 2M floats (e1 rows 0..2047, e2 rows 2048..4095)
    float* Mp0 = ws;             // 4M floats (dead before sim written)
    float* m1  = ws + 4 * M1;    // 1M
    float* m2  = ws + 5 * M1;    // 1M
    float* f1  = ws + 6 * M1;    // 1M
    float* f2  = ws + 7 * M1;    // 1M
    float* ne  = ws + 18 * M1;   // 4096 (ne1) + 4096 (ne2)
    float* lv  = ne + 2 * 4096;  // 4096 (l1) + 4096 (l2)
    float* rmx = lv + 2 * 4096;  // 4096
    int*   n0v = (int*)(rmx + 4096);
    int*   n1v = n0v + 4096;
    int*   id4 = n1v + 4096;     // 4*4096
    float* vls = (float*)(id4 + 4 * 4096); // 4*4096

    // G1: Mp0 = Us^T Ut + iou   (M=2048,N=2048,K=512)
    gemm_f32<<<dim3(Q / TDIM, G / TDIM), 256, 0, stream>>>(
        Us, Ut, Mp0, Q, G, D, 1, 2048, 2048, 1, 2048, iou, 2048, nullptr, 0);
    // G2: m1 = Mp0 * Ut^T       (M=2048,N=512,K=2048)
    gemm_f32<<<dim3(Q / TDIM, D / TDIM), 256, 0, stream>>>(
        Mp0, Ut, m1, Q, D, Q, 2048, 1, 1, 2048, 512, nullptr, 0, nullptr, 0);
    // G3: m2 = Mp0^T * Us^T     (M=2048,N=512,K=2048)
    gemm_f32<<<dim3(Q / TDIM, D / TDIM), 256, 0, stream>>>(
        Mp0, Us, m2, Q, D, Q, 1, 2048, 1, 2048, 512, nullptr, 0, nullptr, 0);

    colsq_kernel<<<Q / 256, 256, 0, stream>>>(Us, ne, D, Q);
    colsq_kernel<<<G / 256, 256, 0, stream>>>(Ut, ne + 2048, D, G);
    lscale_kernel<<<(Q * 64) / 256, 256, 0, stream>>>(m1, ne, lv, Q, D);
    lscale_kernel<<<(G * 64) / 256, 256, 0, stream>>>(m2, ne + 2048, lv + 2048, G, D);
    fbuild_kernel<<<(Q * D) / 256, 256, 0, stream>>>(Us, m1, lv, f1, Q, D, Q);
    fbuild_kernel<<<(G * D) / 256, 256, 0, stream>>>(Ut, m2, lv + 2048, f2, G, D, G);

    // G4/G5: e = relu(f * W^T + b) -> E   (M=2048,N=512,K=512)
    gemm_f32<<<dim3(Q / TDIM, D / TDIM), 256, 0, stream>>>(
        f1, W, E, Q, D, D, 512, 1, 1, 512, 512, nullptr, 0, bias, 1);
    gemm_f32<<<dim3(G / TDIM, D / TDIM), 256, 0, stream>>>(
        f2, W, E + (size_t)Q * D, G, D, D, 512, 1, 1, 512, 512, nullptr, 0, bias, 1);

    normrows_kernel<<<(A * 64) / 256, 256, 0, stream>>>(E, A, D);

    // G6: sim = E E^T  (M=N=4096,K=512)
    gemm_f32<<<dim3(A / TDIM, A / TDIM), 256, 0, stream>>>(
        E, E, sim, A, A, D, 512, 1, 1, 512, 4096, nullptr, 0, nullptr, 0);

    rowscan_kernel<<<A, 256, 0, stream>>>(sim, rmx, n0v, n1v, A);
    setbuild_kernel<<<A / 256, 256, 0, stream>>>(sim, rmx, n0v, n1v, id4, vls, A);
    final_kernel<<<dim3(G / 16, Q / 16), dim3(16, 16), 0, stream>>>(
        sim, rmx, id4, vls, iou, kf, thr, out, Q, G, A);
}

// Round 9
// 937.392 us; speedup vs baseline: 1.5645x; 1.5645x over previous
//
#include <hip/hip_runtime.h>
#include <cmath>
#include <climits>

typedef unsigned short u16;
typedef unsigned int u32;
typedef __attribute__((ext_vector_type(8))) short short8;
typedef __attribute__((ext_vector_type(4))) float f32x4;

__device__ __forceinline__ u16 f2bf(float x) {
    u32 u = __float_as_uint(x);
    return (u16)((u + 0x7FFFu + ((u >> 16) & 1u)) >> 16);   // RNE f32->bf16
}
__device__ __forceinline__ float bf2f(u16 h) {
    return __uint_as_float(((u32)h) << 16);
}

#define BM 128
#define BN 128
#define BK 32

// Split-bf16 (3-term) MFMA GEMM: C[m,n] = sum_k A(m,k)*B(k,n) (+addmat / +bias,relu)
// A(m,k)=A[m*sAm+k*sAk], B(k,n)=B[k*sBk+n*sBn]. M,N mult of 128; K mult of 32.
// LDS planes hold bf16 hi/lo in MFMA fragment-lane order:
//   element (m,k): idx = (m>>4)*512 + ((m&15) + ((k>>3)<<4))*8 + (k&7)
// so compute-side ds_read_b128 at frag*512 + lane*8 is lane-consecutive (conflict-free).
__global__ __launch_bounds__(256)
void gemm_mfma(const float* __restrict__ A, const float* __restrict__ B,
               float* __restrict__ C, int K,
               int sAm, int sAk, int sBk, int sBn, int ldc,
               const float* __restrict__ addmat, int ldadd,
               const float* __restrict__ bias, int do_relu)
{
    __shared__ u16 aH[4096], aL[4096], bH[4096], bL[4096];
    const int t = threadIdx.x;
    const int l = t & 63, w = t >> 6;
    const int wr = w >> 1, wc = w & 1;          // 2x2 wave grid, 64x64 per wave
    const int m0 = blockIdx.x * BM, n0 = blockIdx.y * BN;

    f32x4 acc[4][4];
    const f32x4 zero = {0.f, 0.f, 0.f, 0.f};
#pragma unroll
    for (int i = 0; i < 4; ++i)
#pragma unroll
        for (int j = 0; j < 4; ++j) acc[i][j] = zero;

    for (int k0 = 0; k0 < K; k0 += BK) {
        // ---- stage A tile (128 x 32) ----
        if (sAk == 1) {                          // k-contiguous: vector f32x2 loads
#pragma unroll
            for (int s = 0; s < 8; ++s) {
                int slot = t + s * 256;          // 0..2047
                int m = slot >> 4, kp = slot & 15;
                float2 v = *(const float2*)(A + (size_t)(m0 + m) * sAm + (size_t)(k0 + kp * 2));
                u16 h0 = f2bf(v.x), h1 = f2bf(v.y);
                u16 g0 = f2bf(v.x - bf2f(h0)), g1 = f2bf(v.y - bf2f(h1));
                int idx = (m >> 4) * 512 + ((m & 15) + ((kp >> 2) << 4)) * 8 + (kp & 3) * 2;
                *(ushort2*)&aH[idx] = make_ushort2(h0, h1);
                *(ushort2*)&aL[idx] = make_ushort2(g0, g1);
            }
        } else {                                 // m-contiguous (column-major A)
#pragma unroll
            for (int s = 0; s < 16; ++s) {
                int slot = t + s * 256;          // 0..4095
                int m = slot & 127, kk = slot >> 7;
                float v = A[(size_t)(m0 + m) * sAm + (size_t)(k0 + kk) * sAk];
                u16 h = f2bf(v);
                int idx = (m >> 4) * 512 + ((m & 15) + ((kk >> 3) << 4)) * 8 + (kk & 7);
                aH[idx] = h;
                aL[idx] = f2bf(v - bf2f(h));
            }
        }
        // ---- stage B tile (32 x 128) ----
        if (sBk == 1) {                          // k-contiguous: vector f32x2 loads
#pragma unroll
            for (int s = 0; s < 8; ++s) {
                int slot = t + s * 256;
                int n = slot >> 4, kp = slot & 15;
                float2 v = *(const float2*)(B + (size_t)(n0 + n) * sBn + (size_t)(k0 + kp * 2));
                u16 h0 = f2bf(v.x), h1 = f2bf(v.y);
                u16 g0 = f2bf(v.x - bf2f(h0)), g1 = f2bf(v.y - bf2f(h1));
                int idx = (n >> 4) * 512 + ((n & 15) + ((kp >> 2) << 4)) * 8 + (kp & 3) * 2;
                *(ushort2*)&bH[idx] = make_ushort2(h0, h1);
                *(ushort2*)&bL[idx] = make_ushort2(g0, g1);
            }
        } else {                                 // n-contiguous (sBn==1)
#pragma unroll
            for (int s = 0; s < 16; ++s) {
                int slot = t + s * 256;
                int n = slot & 127, kk = slot >> 7;
                float v = B[(size_t)(k0 + kk) * sBk + (size_t)(n0 + n)];
                u16 h = f2bf(v);
                int idx = (n >> 4) * 512 + ((n & 15) + ((kk >> 3) << 4)) * 8 + (kk & 7);
                bH[idx] = h;
                bL[idx] = f2bf(v - bf2f(h));
            }
        }
        __syncthreads();

        // ---- compute: per wave 4x4 fragments, 3 MFMAs per fragment pair ----
        short8 vbh[4], vbl[4];
#pragma unroll
        for (int j = 0; j < 4; ++j) {
            int f = wc * 4 + j;
            vbh[j] = *(const short8*)&bH[f * 512 + l * 8];
            vbl[j] = *(const short8*)&bL[f * 512 + l * 8];
        }
#pragma unroll
        for (int i = 0; i < 4; ++i) {
            int f = wr * 4 + i;
            short8 ah = *(const short8*)&aH[f * 512 + l * 8];
            short8 al = *(const short8*)&aL[f * 512 + l * 8];
#pragma unroll
            for (int j = 0; j < 4; ++j) {
                acc[i][j] = __builtin_amdgcn_mfma_f32_16x16x32_bf16(ah, vbh[j], acc[i][j], 0, 0, 0);
                acc[i][j] = __builtin_amdgcn_mfma_f32_16x16x32_bf16(ah, vbl[j], acc[i][j], 0, 0, 0);
                acc[i][j] = __builtin_amdgcn_mfma_f32_16x16x32_bf16(al, vbh[j], acc[i][j], 0, 0, 0);
            }
        }
        __syncthreads();
    }

    // ---- epilogue: C/D mapping col=lane&15, row=(lane>>4)*4+reg ----
    const int col_l = l & 15, row_g = l >> 4;
#pragma unroll
    for (int i = 0; i < 4; ++i) {
        int row_base = m0 + (wr * 4 + i) * 16 + row_g * 4;
#pragma unroll
        for (int j = 0; j < 4; ++j) {
            int col = n0 + (wc * 4 + j) * 16 + col_l;
#pragma unroll
            for (int r = 0; r < 4; ++r) {
                int row = row_base + r;
                float v = acc[i][j][r];
                if (addmat) v += addmat[(size_t)row * ldadd + col];
                if (bias)   v += bias[col];
                if (do_relu) v = fmaxf(v, 0.f);
                C[(size_t)row * ldc + col] = v;
            }
        }
    }
}

// ne[i] = sum_d U[d*Ncol + i]^2  (column squared norms, coalesced across i)
__global__ void colsq_kernel(const float* __restrict__ U, float* __restrict__ out,
                             int D, int Ncol)
{
    int i = blockIdx.x * blockDim.x + threadIdx.x;
    if (i >= Ncol) return;
    float s = 0.f;
    for (int d = 0; d < D; ++d) { float v = U[(size_t)d * Ncol + i]; s += v * v; }
    out[i] = s;
}

// l[i] = sqrt(ne[i]) / sqrt(sum_d m[i,d]^2); one wave per row
__global__ void lscale_kernel(const float* __restrict__ m, const float* __restrict__ ne,
                              float* __restrict__ l, int rows, int D)
{
    int gid  = blockIdx.x * blockDim.x + threadIdx.x;
    int wave = gid >> 6;
    int lane = gid & 63;
    if (wave >= rows) return;
    const float* r = m + (size_t)wave * D;
    float s = 0.f;
    for (int d = lane; d < D; d += 64) { float v = r[d]; s += v * v; }
#pragma unroll
    for (int off = 32; off; off >>= 1) s += __shfl_down(s, off);
    if (lane == 0) l[wave] = sqrtf(ne[wave]) / sqrtf(s);
}

// f[i*D+d] = U[d*Ncol+i] + l[i]*m[i*D+d]
__global__ void fbuild_kernel(const float* __restrict__ U, const float* __restrict__ m,
                              const float* __restrict__ l, float* __restrict__ f,
                              int rows, int D, int Ncol)
{
    int idx = blockIdx.x * blockDim.x + threadIdx.x;
    if (idx >= rows * D) return;
    int i = idx / D, d = idx - i * D;
    f[idx] = U[(size_t)d * Ncol + i] + l[i] * m[idx];
}

// row-wise L2 normalize in place: e /= max(||e||, 1e-12); one wave per row
__global__ void normrows_kernel(float* __restrict__ E, int rows, int D)
{
    int gid  = blockIdx.x * blockDim.x + threadIdx.x;
    int wave = gid >> 6;
    int lane = gid & 63;
    if (wave >= rows) return;
    float* r = E + (size_t)wave * D;
    float s = 0.f;
    for (int d = lane; d < D; d += 64) { float v = r[d]; s += v * v; }
#pragma unroll
    for (int off = 32; off; off >>= 1) s += __shfl_xor(s, off);
    float denom = fmaxf(sqrtf(s), 1e-12f);
    for (int d = lane; d < D; d += 64) r[d] = r[d] / denom;
}

// per row a of sim (A x A): dd = (2-2*s)^2 ; rowmax(dd), stable top-2 (value,index)
__global__ __launch_bounds__(256)
void rowscan_kernel(const float* __restrict__ sim, float* __restrict__ rowmax,
                    int* __restrict__ n0, int* __restrict__ n1, int A)
{
    int a = blockIdx.x;
    const float* row = sim + (size_t)a * A;
    int tid = threadIdx.x;
    float vmax = -1e30f;
    float b0v = 1e30f, b1v = 1e30f;
    int   b0i = INT_MAX, b1i = INT_MAX;
    for (int j = tid; j < A; j += 256) {
        float s  = row[j];
        float tt = 2.f - 2.f * s;
        float dd = tt * tt;
        vmax = fmaxf(vmax, dd);
        if (dd < b0v) { b1v = b0v; b1i = b0i; b0v = dd; b0i = j; }
        else if (dd < b1v) { b1v = dd; b1i = j; }
    }
    __shared__ float s_max[256], s_v0[256], s_v1[256];
    __shared__ int   s_i0[256], s_i1[256];
    s_max[tid] = vmax; s_v0[tid] = b0v; s_i0[tid] = b0i; s_v1[tid] = b1v; s_i1[tid] = b1i;
    __syncthreads();
    for (int off = 128; off; off >>= 1) {
        if (tid < off) {
            s_max[tid] = fmaxf(s_max[tid], s_max[tid + off]);
            float a0v = s_v0[tid], a1v = s_v1[tid];
            int   a0i = s_i0[tid], a1i = s_i1[tid];
            float c0v = s_v0[tid + off], c1v = s_v1[tid + off];
            int   c0i = s_i0[tid + off], c1i = s_i1[tid + off];
            float r0v, r1v; int r0i, r1i;
            bool c0_lt_a0 = (c0v < a0v) || (c0v == a0v && c0i < a0i);
            if (c0_lt_a0) {
                r0v = c0v; r0i = c0i;
                bool a0_lt_c1 = (a0v < c1v) || (a0v == c1v && a0i < c1i);
                if (a0_lt_c1) { r1v = a0v; r1i = a0i; } else { r1v = c1v; r1i = c1i; }
            } else {
                r0v = a0v; r0i = a0i;
                bool c0_lt_a1 = (c0v < a1v) || (c0v == a1v && c0i < a1i);
                if (c0_lt_a1) { r1v = c0v; r1i = c0i; } else { r1v = a1v; r1i = a1i; }
            }
            s_v0[tid] = r0v; s_i0[tid] = r0i; s_v1[tid] = r1v; s_i1[tid] = r1i;
        }
        __syncthreads();
    }
    if (tid == 0) { rowmax[a] = s_max[0]; n0[a] = s_i0[0]; n1[a] = s_i1[0]; }
}

// per-row k-reciprocal expansion set (k1=1): idx4, vals
__global__ void setbuild_kernel(const float* __restrict__ sim, const float* __restrict__ rmx,
                                const int* __restrict__ n0, const int* __restrict__ n1,
                                int* __restrict__ idx4, float* __restrict__ vals, int A)
{
    int a = blockIdx.x * blockDim.x + threadIdx.x;
    if (a >= A) return;
    int c0 = n0[a], c1 = n1[a];
    bool v0 = (n0[c0] == a) || (n1[c0] == a);
    bool v1 = (n0[c1] == a) || (n1[c1] == a);
    int e0 = n0[c0], e1 = n0[c1];
    bool inR_e0 = (v0 && e0 == c0) || (v1 && e0 == c1);
    bool inR_e1 = (v0 && e1 == c0) || (v1 && e1 == c1);
    bool v2 = v0 && (n0[e0] == c0) && inR_e0;
    bool v3 = v1 && (n0[e1] == c1) && inR_e1;
    int  id[4]  = { c0, c1, e0, e1 };
    bool raw[4] = { v0, v1, v2, v3 };
    bool kept[4];
    kept[0] = raw[0];
#pragma unroll
    for (int j = 1; j < 4; ++j) {
        bool dup = false;
        for (int k = 0; k < j; ++k) dup = dup || (kept[k] && id[k] == id[j]);
        kept[j] = raw[j] && !dup;
    }
    float rm = rmx[a];
    const float* row = sim + (size_t)a * A;
    float wv[4]; float wsum = 0.f;
#pragma unroll
    for (int k = 0; k < 4; ++k) {
        float s  = row[id[k]];
        float tt = 2.f - 2.f * s;
        float dd = tt * tt / rm;
        wv[k] = kept[k] ? expf(-dd) : 0.f;
        wsum += wv[k];
    }
    float den = (wsum > 0.f) ? wsum : 1.f;
#pragma unroll
    for (int k = 0; k < 4; ++k) {
        idx4[a * 4 + k] = id[k];
        vals[a * 4 + k] = wv[k] / den;
    }
}

// outputs: Mp_before, Mp = 1 - (0.7*jac + 0.3*d), thr_flag
__global__ __launch_bounds__(256)
void final_kernel(const float* __restrict__ sim, const float* __restrict__ rmx,
                  const int* __restrict__ idx4, const float* __restrict__ vals,
                  const float* __restrict__ iou, const float* __restrict__ kf,
                  const float* __restrict__ thr, float* __restrict__ out,
                  int Q, int G, int A)
{
    int j = blockIdx.x * 16 + threadIdx.x;
    int i = blockIdx.y * 16 + threadIdx.y;
    if (i >= Q || j >= G) return;
    int b = Q + j;
    float s = sim[(size_t)i * A + b];   // Mp_before[i][j]
    int   ia[4], ib[4];
    float va[4], vb[4];
#pragma unroll
    for (int k = 0; k < 4; ++k) {
        ia[k] = idx4[i * 4 + k]; va[k] = vals[i * 4 + k];
        ib[k] = idx4[b * 4 + k]; vb[k] = vals[b * 4 + k];
    }
    float tt0 = 0.f;
#pragma unroll
    for (int k = 0; k < 4; ++k) {
        float sm = 0.f;
#pragma unroll
        for (int m = 0; m < 4; ++m) sm += (ib[m] == ia[k]) ? vb[m] : 0.f;
        tt0 += fminf(va[k], sm);
    }
    float jac = 1.f - tt0 / (2.f - tt0);
    float tt  = 2.f - 2.f * s;
    float dqg = tt * tt / rmx[i];
    float fin = jac * 0.7f + dqg * 0.3f;
    size_t o  = (size_t)i * G + j;
    size_t QG = (size_t)Q * G;
    out[o]          = s;
    out[QG + o]     = 1.f - fin;
    float iv = iou[o], kv = kf[o];
    out[2 * QG + o] = (kv == -1.f || iv == 0.f || s < thr[0]) ? 1.f : 0.f;
}

extern "C" void kernel_launch(void* const* d_in, const int* in_sizes, int n_in,
                              void* d_out, int out_size, void* d_ws, size_t ws_size,
                              hipStream_t stream)
{
    const float* Us   = (const float*)d_in[0];  // (512, 2048)
    const float* Ut   = (const float*)d_in[1];  // (512, 2048)
    const float* iou  = (const float*)d_in[2];  // (2048, 2048)
    const float* kf   = (const float*)d_in[3];  // (2048, 2048)
    const float* thr  = (const float*)d_in[4];  // (1,)
    const float* W    = (const float*)d_in[5];  // (512, 512)
    const float* bias = (const float*)d_in[6];  // (512,)
    float* out = (float*)d_out;

    const int Q = 2048, G = 2048, D = 512, A = 4096;
    const size_t M1 = 1024 * 1024;

    float* ws  = (float*)d_ws;
    // Aliased layout (peak ~72.5 MB):
    float* sim = ws;             // 16M floats; written at G6 (early bufs dead by then)
    float* E   = ws + 16 * M1;   // 2M floats (e1 rows 0..2047, e2 rows 2048..4095)
    float* Mp0 = ws;             // 4M floats (dead before sim written)
    float* m1  = ws + 4 * M1;    // 1M
    float* m2  = ws + 5 * M1;    // 1M
    float* f1  = ws + 6 * M1;    // 1M
    float* f2  = ws + 7 * M1;    // 1M
    float* ne  = ws + 18 * M1;   // 4096 (ne1) + 4096 (ne2)
    float* lv  = ne + 2 * 4096;  // 4096 (l1) + 4096 (l2)
    float* rmx = lv + 2 * 4096;  // 4096
    int*   n0v = (int*)(rmx + 4096);
    int*   n1v = n0v + 4096;
    int*   id4 = n1v + 4096;     // 4*4096
    float* vls = (float*)(id4 + 4 * 4096); // 4*4096

    // G1: Mp0 = Us^T Ut + iou   (M=2048,N=2048,K=512)  A(m,k)=Us[k*2048+m], B(k,n)=Ut[k*2048+n]
    gemm_mfma<<<dim3(Q / BM, G / BN), 256, 0, stream>>>(
        Us, Ut, Mp0, D, 1, 2048, 2048, 1, 2048, iou, 2048, nullptr, 0);
    // G2: m1 = Mp0 * Ut^T       (M=2048,N=512,K=2048)  B(k,n)=Ut[n*2048+k]
    gemm_mfma<<<dim3(Q / BM, D / BN), 256, 0, stream>>>(
        Mp0, Ut, m1, Q, 2048, 1, 1, 2048, 512, nullptr, 0, nullptr, 0);
    // G3: m2 = Mp0^T * Us^T     (M=2048,N=512,K=2048)  A(m,k)=Mp0[k*2048+m], B(k,n)=Us[n*2048+k]
    gemm_mfma<<<dim3(Q / BM, D / BN), 256, 0, stream>>>(
        Mp0, Us, m2, Q, 1, 2048, 1, 2048, 512, nullptr, 0, nullptr, 0);

    colsq_kernel<<<Q / 256, 256, 0, stream>>>(Us, ne, D, Q);
    colsq_kernel<<<G / 256, 256, 0, stream>>>(Ut, ne + 2048, D, G);
    lscale_kernel<<<(Q * 64) / 256, 256, 0, stream>>>(m1, ne, lv, Q, D);
    lscale_kernel<<<(G * 64) / 256, 256, 0, stream>>>(m2, ne + 2048, lv + 2048, G, D);
    fbuild_kernel<<<(Q * D) / 256, 256, 0, stream>>>(Us, m1, lv, f1, Q, D, Q);
    fbuild_kernel<<<(G * D) / 256, 256, 0, stream>>>(Ut, m2, lv + 2048, f2, G, D, G);

    // G4/G5: e = relu(f * W^T + b) -> E   (M=2048,N=512,K=512)  B(k,n)=W[n*512+k]
    gemm_mfma<<<dim3(Q / BM, D / BN), 256, 0, stream>>>(
        f1, W, E, D, 512, 1, 1, 512, 512, nullptr, 0, bias, 1);
    gemm_mfma<<<dim3(G / BM, D / BN), 256, 0, stream>>>(
        f2, W, E + (size_t)Q * D, D, 512, 1, 1, 512, 512, nullptr, 0, bias, 1);

    normrows_kernel<<<(A * 64) / 256, 256, 0, stream>>>(E, A, D);

    // G6: sim = E E^T  (M=N=4096,K=512)  A(m,k)=E[m*512+k], B(k,n)=E[n*512+k]
    gemm_mfma<<<dim3(A / BM, A / BN), 256, 0, stream>>>(
        E, E, sim, D, 512, 1, 1, 512, 4096, nullptr, 0, nullptr, 0);

    rowscan_kernel<<<A, 256, 0, stream>>>(sim, rmx, n0v, n1v, A);
    setbuild_kernel<<<A / 256, 256, 0, stream>>>(sim, rmx, n0v, n1v, id4, vls, A);
    final_kernel<<<dim3(G / 16, Q / 16), dim3(16, 16), 0, stream>>>(
        sim, rmx, id4, vls, iou, kf, thr, out, Q, G, A);
}

// Round 16
// 671.510 us; speedup vs baseline: 2.1839x; 1.3959x over previous
//
#include <hip/hip_runtime.h>
#include <cmath>
#include <climits>

typedef unsigned short u16;
typedef unsigned int u32;
typedef __attribute__((ext_vector_type(8))) short short8;
typedef __attribute__((ext_vector_type(4))) float f32x4;

__device__ __forceinline__ u16 f2bf(float x) {
    u32 u = __float_as_uint(x);
    return (u16)((u + 0x7FFFu + ((u >> 16) & 1u)) >> 16);   // RNE f32->bf16
}
__device__ __forceinline__ float bf2f(u16 h) {
    return __uint_as_float(((u32)h) << 16);
}

#define BM 128
#define BN 128
#define BK 32

// Split-bf16 (3-term) MFMA GEMM with optional split-K.
// C[m,n] = sum_{k in [z*kchunk, min(K,(z+1)*kchunk))} A(m,k)*B(k,n); z = blockIdx.z
// writes to C + z*zstride. Epilogue (addmat/bias/relu) only valid for gridDim.z==1.
__global__ __launch_bounds__(256)
void gemm_mfma(const float* __restrict__ A, const float* __restrict__ B,
               float* __restrict__ C, int K, int kchunk, size_t zstride,
               int sAm, int sAk, int sBk, int sBn, int ldc,
               const float* __restrict__ addmat, int ldadd,
               const float* __restrict__ bias, int do_relu)
{
    __shared__ u16 aH[4096], aL[4096], bH[4096], bL[4096];
    const int t = threadIdx.x;
    const int l = t & 63, w = t >> 6;
    const int wr = w >> 1, wc = w & 1;          // 2x2 wave grid, 64x64 per wave
    const int m0 = blockIdx.x * BM, n0 = blockIdx.y * BN;
    const int kbeg = blockIdx.z * kchunk;
    int kend = kbeg + kchunk; if (kend > K) kend = K;
    float* Cz = C + (size_t)blockIdx.z * zstride;

    f32x4 acc[4][4];
    const f32x4 zero = {0.f, 0.f, 0.f, 0.f};
#pragma unroll
    for (int i = 0; i < 4; ++i)
#pragma unroll
        for (int j = 0; j < 4; ++j) acc[i][j] = zero;

    for (int k0 = kbeg; k0 < kend; k0 += BK) {
        // ---- stage A tile (128 x 32) ----
        if (sAk == 1) {                          // k-contiguous: vector f32x2 loads
#pragma unroll
            for (int s = 0; s < 8; ++s) {
                int slot = t + s * 256;          // 0..2047
                int m = slot >> 4, kp = slot & 15;
                float2 v = *(const float2*)(A + (size_t)(m0 + m) * sAm + (size_t)(k0 + kp * 2));
                u16 h0 = f2bf(v.x), h1 = f2bf(v.y);
                u16 g0 = f2bf(v.x - bf2f(h0)), g1 = f2bf(v.y - bf2f(h1));
                int idx = (m >> 4) * 512 + ((m & 15) + ((kp >> 2) << 4)) * 8 + (kp & 3) * 2;
                *(ushort2*)&aH[idx] = make_ushort2(h0, h1);
                *(ushort2*)&aL[idx] = make_ushort2(g0, g1);
            }
        } else {                                 // m-contiguous (column-major A)
#pragma unroll
            for (int s = 0; s < 16; ++s) {
                int slot = t + s * 256;          // 0..4095
                int m = slot & 127, kk = slot >> 7;
                float v = A[(size_t)(m0 + m) * sAm + (size_t)(k0 + kk) * sAk];
                u16 h = f2bf(v);
                int idx = (m >> 4) * 512 + ((m & 15) + ((kk >> 3) << 4)) * 8 + (kk & 7);
                aH[idx] = h;
                aL[idx] = f2bf(v - bf2f(h));
            }
        }
        // ---- stage B tile (32 x 128) ----
        if (sBk == 1) {                          // k-contiguous: vector f32x2 loads
#pragma unroll
            for (int s = 0; s < 8; ++s) {
                int slot = t + s * 256;
                int n = slot >> 4, kp = slot & 15;
                float2 v = *(const float2*)(B + (size_t)(n0 + n) * sBn + (size_t)(k0 + kp * 2));
                u16 h0 = f2bf(v.x), h1 = f2bf(v.y);
                u16 g0 = f2bf(v.x - bf2f(h0)), g1 = f2bf(v.y - bf2f(h1));
                int idx = (n >> 4) * 512 + ((n & 15) + ((kp >> 2) << 4)) * 8 + (kp & 3) * 2;
                *(ushort2*)&bH[idx] = make_ushort2(h0, h1);
                *(ushort2*)&bL[idx] = make_ushort2(g0, g1);
            }
        } else {                                 // n-contiguous (sBn==1)
#pragma unroll
            for (int s = 0; s < 16; ++s) {
                int slot = t + s * 256;
                int n = slot & 127, kk = slot >> 7;
                float v = B[(size_t)(k0 + kk) * sBk + (size_t)(n0 + n)];
                u16 h = f2bf(v);
                int idx = (n >> 4) * 512 + ((n & 15) + ((kk >> 3) << 4)) * 8 + (kk & 7);
                bH[idx] = h;
                bL[idx] = f2bf(v - bf2f(h));
            }
        }
        __syncthreads();

        // ---- compute: per wave 4x4 fragments, 3 MFMAs per fragment pair ----
        short8 vbh[4], vbl[4];
#pragma unroll
        for (int j = 0; j < 4; ++j) {
            int f = wc * 4 + j;
            vbh[j] = *(const short8*)&bH[f * 512 + l * 8];
            vbl[j] = *(const short8*)&bL[f * 512 + l * 8];
        }
#pragma unroll
        for (int i = 0; i < 4; ++i) {
            int f = wr * 4 + i;
            short8 ah = *(const short8*)&aH[f * 512 + l * 8];
            short8 al = *(const short8*)&aL[f * 512 + l * 8];
#pragma unroll
            for (int j = 0; j < 4; ++j) {
                acc[i][j] = __builtin_amdgcn_mfma_f32_16x16x32_bf16(ah, vbh[j], acc[i][j], 0, 0, 0);
                acc[i][j] = __builtin_amdgcn_mfma_f32_16x16x32_bf16(ah, vbl[j], acc[i][j], 0, 0, 0);
                acc[i][j] = __builtin_amdgcn_mfma_f32_16x16x32_bf16(al, vbh[j], acc[i][j], 0, 0, 0);
            }
        }
        __syncthreads();
    }

    // ---- epilogue: C/D mapping col=lane&15, row=(lane>>4)*4+reg ----
    const int col_l = l & 15, row_g = l >> 4;
#pragma unroll
    for (int i = 0; i < 4; ++i) {
        int row_base = m0 + (wr * 4 + i) * 16 + row_g * 4;
#pragma unroll
        for (int j = 0; j < 4; ++j) {
            int col = n0 + (wc * 4 + j) * 16 + col_l;
#pragma unroll
            for (int r = 0; r < 4; ++r) {
                int row = row_base + r;
                float v = acc[i][j][r];
                if (addmat) v += addmat[(size_t)row * ldadd + col];
                if (bias)   v += bias[col];
                if (do_relu) v = fmaxf(v, 0.f);
                Cz[(size_t)row * ldc + col] = v;
            }
        }
    }
}

// C[i] = sum_{s<S} P[s*MN + i], then optional +bias[col] and relu. float4 per thread.
// MN and N multiples of 4; N power of two.
__global__ __launch_bounds__(256)
void reduce_splitk(const float* __restrict__ P, float* __restrict__ C,
                   int S, size_t MN, const float* __restrict__ bias, int N, int do_relu)
{
    size_t base = ((size_t)blockIdx.x * 256 + threadIdx.x) * 4;
    if (base >= MN) return;
    float4 acc = *(const float4*)(P + base);
    for (int s = 1; s < S; ++s) {
        float4 v = *(const float4*)(P + (size_t)s * MN + base);
        acc.x += v.x; acc.y += v.y; acc.z += v.z; acc.w += v.w;
    }
    if (bias) {
        int col = (int)(base & (size_t)(N - 1));
        acc.x += bias[col]; acc.y += bias[col + 1]; acc.z += bias[col + 2]; acc.w += bias[col + 3];
    }
    if (do_relu) {
        acc.x = fmaxf(acc.x, 0.f); acc.y = fmaxf(acc.y, 0.f);
        acc.z = fmaxf(acc.z, 0.f); acc.w = fmaxf(acc.w, 0.f);
    }
    *(float4*)(C + base) = acc;
}

// ne[i] = sum_d U[d*Ncol + i]^2  (column squared norms, coalesced across i)
__global__ void colsq_kernel(const float* __restrict__ U, float* __restrict__ out,
                             int D, int Ncol)
{
    int i = blockIdx.x * blockDim.x + threadIdx.x;
    if (i >= Ncol) return;
    float s = 0.f;
    for (int d = 0; d < D; ++d) { float v = U[(size_t)d * Ncol + i]; s += v * v; }
    out[i] = s;
}

// l[i] = sqrt(ne[i]) / sqrt(sum_d m[i,d]^2); one wave per row
__global__ void lscale_kernel(const float* __restrict__ m, const float* __restrict__ ne,
                              float* __restrict__ l, int rows, int D)
{
    int gid  = blockIdx.x * blockDim.x + threadIdx.x;
    int wave = gid >> 6;
    int lane = gid & 63;
    if (wave >= rows) return;
    const float* r = m + (size_t)wave * D;
    float s = 0.f;
    for (int d = lane; d < D; d += 64) { float v = r[d]; s += v * v; }
#pragma unroll
    for (int off = 32; off; off >>= 1) s += __shfl_down(s, off);
    if (lane == 0) l[wave] = sqrtf(ne[wave]) / sqrtf(s);
}

// f[i*D+d] = U[d*Ncol+i] + l[i]*m[i*D+d]
__global__ void fbuild_kernel(const float* __restrict__ U, const float* __restrict__ m,
                              const float* __restrict__ l, float* __restrict__ f,
                              int rows, int D, int Ncol)
{
    int idx = blockIdx.x * blockDim.x + threadIdx.x;
    if (idx >= rows * D) return;
    int i = idx / D, d = idx - i * D;
    f[idx] = U[(size_t)d * Ncol + i] + l[i] * m[idx];
}

// row-wise L2 normalize in place: e /= max(||e||, 1e-12); one wave per row
__global__ void normrows_kernel(float* __restrict__ E, int rows, int D)
{
    int gid  = blockIdx.x * blockDim.x + threadIdx.x;
    int wave = gid >> 6;
    int lane = gid & 63;
    if (wave >= rows) return;
    float* r = E + (size_t)wave * D;
    float s = 0.f;
    for (int d = lane; d < D; d += 64) { float v = r[d]; s += v * v; }
#pragma unroll
    for (int off = 32; off; off >>= 1) s += __shfl_xor(s, off);
    float denom = fmaxf(sqrtf(s), 1e-12f);
    for (int d = lane; d < D; d += 64) r[d] = r[d] / denom;
}

// per row a of sim (A x A): dd = (2-2*s)^2 ; rowmax(dd), stable top-2 (value,index)
__global__ __launch_bounds__(256)
void rowscan_kernel(const float* __restrict__ sim, float* __restrict__ rowmax,
                    int* __restrict__ n0, int* __restrict__ n1, int A)
{
    int a = blockIdx.x;
    const float* row = sim + (size_t)a * A;
    int tid = threadIdx.x;
    float vmax = -1e30f;
    float b0v = 1e30f, b1v = 1e30f;
    int   b0i = INT_MAX, b1i = INT_MAX;
    for (int j = tid; j < A; j += 256) {
        float s  = row[j];
        float tt = 2.f - 2.f * s;
        float dd = tt * tt;
        vmax = fmaxf(vmax, dd);
        if (dd < b0v) { b1v = b0v; b1i = b0i; b0v = dd; b0i = j; }
        else if (dd < b1v) { b1v = dd; b1i = j; }
    }
    __shared__ float s_max[256], s_v0[256], s_v1[256];
    __shared__ int   s_i0[256], s_i1[256];
    s_max[tid] = vmax; s_v0[tid] = b0v; s_i0[tid] = b0i; s_v1[tid] = b1v; s_i1[tid] = b1i;
    __syncthreads();
    for (int off = 128; off; off >>= 1) {
        if (tid < off) {
            s_max[tid] = fmaxf(s_max[tid], s_max[tid + off]);
            float a0v = s_v0[tid], a1v = s_v1[tid];
            int   a0i = s_i0[tid], a1i = s_i1[tid];
            float c0v = s_v0[tid + off], c1v = s_v1[tid + off];
            int   c0i = s_i0[tid + off], c1i = s_i1[tid + off];
            float r0v, r1v; int r0i, r1i;
            bool c0_lt_a0 = (c0v < a0v) || (c0v == a0v && c0i < a0i);
            if (c0_lt_a0) {
                r0v = c0v; r0i = c0i;
                bool a0_lt_c1 = (a0v < c1v) || (a0v == c1v && a0i < c1i);
                if (a0_lt_c1) { r1v = a0v; r1i = a0i; } else { r1v = c1v; r1i = c1i; }
            } else {
                r0v = a0v; r0i = a0i;
                bool c0_lt_a1 = (c0v < a1v) || (c0v == a1v && c0i < a1i);
                if (c0_lt_a1) { r1v = c0v; r1i = c0i; } else { r1v = a1v; r1i = a1i; }
            }
            s_v0[tid] = r0v; s_i0[tid] = r0i; s_v1[tid] = r1v; s_i1[tid] = r1i;
        }
        __syncthreads();
    }
    if (tid == 0) { rowmax[a] = s_max[0]; n0[a] = s_i0[0]; n1[a] = s_i1[0]; }
}

// per-row k-reciprocal expansion set (k1=1): idx4, vals
__global__ void setbuild_kernel(const float* __restrict__ sim, const float* __restrict__ rmx,
                                const int* __restrict__ n0, const int* __restrict__ n1,
                                int* __restrict__ idx4, float* __restrict__ vals, int A)
{
    int a = blockIdx.x * blockDim.x + threadIdx.x;
    if (a >= A) return;
    int c0 = n0[a], c1 = n1[a];
    bool v0 = (n0[c0] == a) || (n1[c0] == a);
    bool v1 = (n0[c1] == a) || (n1[c1] == a);
    int e0 = n0[c0], e1 = n0[c1];
    bool inR_e0 = (v0 && e0 == c0) || (v1 && e0 == c1);
    bool inR_e1 = (v0 && e1 == c0) || (v1 && e1 == c1);
    bool v2 = v0 && (n0[e0] == c0) && inR_e0;
    bool v3 = v1 && (n0[e1] == c1) && inR_e1;
    int  id[4]  = { c0, c1, e0, e1 };
    bool raw[4] = { v0, v1, v2, v3 };
    bool kept[4];
    kept[0] = raw[0];
#pragma unroll
    for (int j = 1; j < 4; ++j) {
        bool dup = false;
        for (int k = 0; k < j; ++k) dup = dup || (kept[k] && id[k] == id[j]);
        kept[j] = raw[j] && !dup;
    }
    float rm = rmx[a];
    const float* row = sim + (size_t)a * A;
    float wv[4]; float wsum = 0.f;
#pragma unroll
    for (int k = 0; k < 4; ++k) {
        float s  = row[id[k]];
        float tt = 2.f - 2.f * s;
        float dd = tt * tt / rm;
        wv[k] = kept[k] ? expf(-dd) : 0.f;
        wsum += wv[k];
    }
    float den = (wsum > 0.f) ? wsum : 1.f;
#pragma unroll
    for (int k = 0; k < 4; ++k) {
        idx4[a * 4 + k] = id[k];
        vals[a * 4 + k] = wv[k] / den;
    }
}

// outputs: Mp_before, Mp = 1 - (0.7*jac + 0.3*d), thr_flag
__global__ __launch_bounds__(256)
void final_kernel(const float* __restrict__ sim, const float* __restrict__ rmx,
                  const int* __restrict__ idx4, const float* __restrict__ vals,
                  const float* __restrict__ iou, const float* __restrict__ kf,
                  const float* __restrict__ thr, float* __restrict__ out,
                  int Q, int G, int A)
{
    int j = blockIdx.x * 16 + threadIdx.x;
    int i = blockIdx.y * 16 + threadIdx.y;
    if (i >= Q || j >= G) return;
    int b = Q + j;
    float s = sim[(size_t)i * A + b];   // Mp_before[i][j]
    int   ia[4], ib[4];
    float va[4], vb[4];
#pragma unroll
    for (int k = 0; k < 4; ++k) {
        ia[k] = idx4[i * 4 + k]; va[k] = vals[i * 4 + k];
        ib[k] = idx4[b * 4 + k]; vb[k] = vals[b * 4 + k];
    }
    float tt0 = 0.f;
#pragma unroll
    for (int k = 0; k < 4; ++k) {
        float sm = 0.f;
#pragma unroll
        for (int m = 0; m < 4; ++m) sm += (ib[m] == ia[k]) ? vb[m] : 0.f;
        tt0 += fminf(va[k], sm);
    }
    float jac = 1.f - tt0 / (2.f - tt0);
    float tt  = 2.f - 2.f * s;
    float dqg = tt * tt / rmx[i];
    float fin = jac * 0.7f + dqg * 0.3f;
    size_t o  = (size_t)i * G + j;
    size_t QG = (size_t)Q * G;
    out[o]          = s;
    out[QG + o]     = 1.f - fin;
    float iv = iou[o], kv = kf[o];
    out[2 * QG + o] = (kv == -1.f || iv == 0.f || s < thr[0]) ? 1.f : 0.f;
}

extern "C" void kernel_launch(void* const* d_in, const int* in_sizes, int n_in,
                              void* d_out, int out_size, void* d_ws, size_t ws_size,
                              hipStream_t stream)
{
    const float* Us   = (const float*)d_in[0];  // (512, 2048)
    const float* Ut   = (const float*)d_in[1];  // (512, 2048)
    const float* iou  = (const float*)d_in[2];  // (2048, 2048)
    const float* kf   = (const float*)d_in[3];  // (2048, 2048)
    const float* thr  = (const float*)d_in[4];  // (1,)
    const float* W    = (const float*)d_in[5];  // (512, 512)
    const float* bias = (const float*)d_in[6];  // (512,)
    float* out = (float*)d_out;

    const int Q = 2048, G = 2048, D = 512, A = 4096;
    const size_t M1 = 1024 * 1024;
    const size_t MN = (size_t)Q * D;            // 1M floats (2048x512 outputs)

    float* ws  = (float*)d_ws;
    // Aliased layout (peak ~72.5 MB):
    float* sim = ws;             // 16M floats; written at G6 (early bufs dead by then)
    float* E   = ws + 16 * M1;   // 2M floats (e1 rows 0..2047, e2 rows 2048..4095)
    float* Mp0 = ws;             // 4M floats (dead before sim written)
    float* m1  = ws + 4 * M1;    // 1M
    float* m2  = ws + 5 * M1;    // 1M
    float* f1  = ws + 6 * M1;    // 1M
    float* f2  = ws + 7 * M1;    // 1M
    float* Pk  = ws + 8 * M1;    // split-K partials: up to 8M floats [8M1,16M1), free here
    float* ne  = ws + 18 * M1;   // 4096 (ne1) + 4096 (ne2)
    float* lv  = ne + 2 * 4096;  // 4096 (l1) + 4096 (l2)
    float* rmx = lv + 2 * 4096;  // 4096
    int*   n0v = (int*)(rmx + 4096);
    int*   n1v = n0v + 4096;
    int*   id4 = n1v + 4096;     // 4*4096
    float* vls = (float*)(id4 + 4 * 4096); // 4*4096

    // G1: Mp0 = Us^T Ut + iou   (M=2048,N=2048,K=512)  A(m,k)=Us[k*2048+m], B(k,n)=Ut[k*2048+n]
    gemm_mfma<<<dim3(Q / BM, G / BN, 1), 256, 0, stream>>>(
        Us, Ut, Mp0, D, D, 0, 1, 2048, 2048, 1, 2048, iou, 2048, nullptr, 0);

    // G2: m1 = Mp0 * Ut^T  (M=2048,N=512,K=2048), split-K 8 -> 512 blocks
    gemm_mfma<<<dim3(Q / BM, D / BN, 8), 256, 0, stream>>>(
        Mp0, Ut, Pk, Q, Q / 8, MN, 2048, 1, 1, 2048, 512, nullptr, 0, nullptr, 0);
    reduce_splitk<<<(int)(MN / 1024), 256, 0, stream>>>(Pk, m1, 8, MN, nullptr, D, 0);
    // G3: m2 = Mp0^T * Us^T  (M=2048,N=512,K=2048), split-K 8
    gemm_mfma<<<dim3(Q / BM, D / BN, 8), 256, 0, stream>>>(
        Mp0, Us, Pk, Q, Q / 8, MN, 1, 2048, 1, 2048, 512, nullptr, 0, nullptr, 0);
    reduce_splitk<<<(int)(MN / 1024), 256, 0, stream>>>(Pk, m2, 8, MN, nullptr, D, 0);

    colsq_kernel<<<Q / 256, 256, 0, stream>>>(Us, ne, D, Q);
    colsq_kernel<<<G / 256, 256, 0, stream>>>(Ut, ne + 2048, D, G);
    lscale_kernel<<<(Q * 64) / 256, 256, 0, stream>>>(m1, ne, lv, Q, D);
    lscale_kernel<<<(G * 64) / 256, 256, 0, stream>>>(m2, ne + 2048, lv + 2048, G, D);
    fbuild_kernel<<<(Q * D) / 256, 256, 0, stream>>>(Us, m1, lv, f1, Q, D, Q);
    fbuild_kernel<<<(G * D) / 256, 256, 0, stream>>>(Ut, m2, lv + 2048, f2, G, D, G);

    // G4/G5: e = relu(f * W^T + b) -> E  (M=2048,N=512,K=512), split-K 4 -> 256 blocks
    gemm_mfma<<<dim3(Q / BM, D / BN, 4), 256, 0, stream>>>(
        f1, W, Pk, D, D / 4, MN, 512, 1, 1, 512, 512, nullptr, 0, nullptr, 0);
    reduce_splitk<<<(int)(MN / 1024), 256, 0, stream>>>(Pk, E, 4, MN, bias, D, 1);
    gemm_mfma<<<dim3(G / BM, D / BN, 4), 256, 0, stream>>>(
        f2, W, Pk, D, D / 4, MN, 512, 1, 1, 512, 512, nullptr, 0, nullptr, 0);
    reduce_splitk<<<(int)(MN / 1024), 256, 0, stream>>>(Pk, E + (size_t)Q * D, 4, MN, bias, D, 1);

    normrows_kernel<<<(A * 64) / 256, 256, 0, stream>>>(E, A, D);

    // G6: sim = E E^T  (M=N=4096,K=512)  A(m,k)=E[m*512+k], B(k,n)=E[n*512+k]
    gemm_mfma<<<dim3(A / BM, A / BN, 1), 256, 0, stream>>>(
        E, E, sim, D, D, 0, 512, 1, 1, 512, 4096, nullptr, 0, nullptr, 0);

    rowscan_kernel<<<A, 256, 0, stream>>>(sim, rmx, n0v, n1v, A);
    setbuild_kernel<<<A / 256, 256, 0, stream>>>(sim, rmx, n0v, n1v, id4, vls, A);
    final_kernel<<<dim3(G / 16, Q / 16), dim3(16, 16), 0, stream>>>(
        sim, rmx, id4, vls, iou, kf, thr, out, Q, G, A);
}

// Round 17
// 465.449 us; speedup vs baseline: 3.1508x; 1.4427x over previous
//
#include <hip/hip_runtime.h>
#include <cmath>
#include <climits>

typedef unsigned short u16;
typedef unsigned int u32;
typedef __attribute__((ext_vector_type(8))) short short8;
typedef __attribute__((ext_vector_type(4))) float f32x4;

__device__ __forceinline__ u16 f2bf(float x) {
    u32 u = __float_as_uint(x);
    return (u16)((u + 0x7FFFu + ((u >> 16) & 1u)) >> 16);   // RNE f32->bf16
}
__device__ __forceinline__ float bf2f(u16 h) {
    return __uint_as_float(((u32)h) << 16);
}

#define BM 128
#define BN 128
#define BK 32

// Split-bf16 (3-term) MFMA GEMM with optional split-K.
// C[m,n] = sum_{k in [z*kchunk, min(K,(z+1)*kchunk))} A(m,k)*B(k,n); z = blockIdx.z
// writes to C + z*zstride. Epilogue (addmat/bias/relu) only valid for gridDim.z==1.
__global__ __launch_bounds__(256)
void gemm_mfma(const float* __restrict__ A, const float* __restrict__ B,
               float* __restrict__ C, int K, int kchunk, size_t zstride,
               int sAm, int sAk, int sBk, int sBn, int ldc,
               const float* __restrict__ addmat, int ldadd,
               const float* __restrict__ bias, int do_relu)
{
    __shared__ u16 aH[4096], aL[4096], bH[4096], bL[4096];
    const int t = threadIdx.x;
    const int l = t & 63, w = t >> 6;
    const int wr = w >> 1, wc = w & 1;          // 2x2 wave grid, 64x64 per wave
    const int m0 = blockIdx.x * BM, n0 = blockIdx.y * BN;
    const int kbeg = blockIdx.z * kchunk;
    int kend = kbeg + kchunk; if (kend > K) kend = K;
    float* Cz = C + (size_t)blockIdx.z * zstride;

    f32x4 acc[4][4];
    const f32x4 zero = {0.f, 0.f, 0.f, 0.f};
#pragma unroll
    for (int i = 0; i < 4; ++i)
#pragma unroll
        for (int j = 0; j < 4; ++j) acc[i][j] = zero;

    for (int k0 = kbeg; k0 < kend; k0 += BK) {
        // ---- stage A tile (128 x 32) ----
        if (sAk == 1) {                          // k-contiguous: vector f32x2 loads
#pragma unroll
            for (int s = 0; s < 8; ++s) {
                int slot = t + s * 256;          // 0..2047
                int m = slot >> 4, kp = slot & 15;
                float2 v = *(const float2*)(A + (size_t)(m0 + m) * sAm + (size_t)(k0 + kp * 2));
                u16 h0 = f2bf(v.x), h1 = f2bf(v.y);
                u16 g0 = f2bf(v.x - bf2f(h0)), g1 = f2bf(v.y - bf2f(h1));
                int idx = (m >> 4) * 512 + ((m & 15) + ((kp >> 2) << 4)) * 8 + (kp & 3) * 2;
                *(ushort2*)&aH[idx] = make_ushort2(h0, h1);
                *(ushort2*)&aL[idx] = make_ushort2(g0, g1);
            }
        } else {                                 // m-contiguous (column-major A)
#pragma unroll
            for (int s = 0; s < 16; ++s) {
                int slot = t + s * 256;          // 0..4095
                int m = slot & 127, kk = slot >> 7;
                float v = A[(size_t)(m0 + m) * sAm + (size_t)(k0 + kk) * sAk];
                u16 h = f2bf(v);
                int idx = (m >> 4) * 512 + ((m & 15) + ((kk >> 3) << 4)) * 8 + (kk & 7);
                aH[idx] = h;
                aL[idx] = f2bf(v - bf2f(h));
            }
        }
        // ---- stage B tile (32 x 128) ----
        if (sBk == 1) {                          // k-contiguous: vector f32x2 loads
#pragma unroll
            for (int s = 0; s < 8; ++s) {
                int slot = t + s * 256;
                int n = slot >> 4, kp = slot & 15;
                float2 v = *(const float2*)(B + (size_t)(n0 + n) * sBn + (size_t)(k0 + kp * 2));
                u16 h0 = f2bf(v.x), h1 = f2bf(v.y);
                u16 g0 = f2bf(v.x - bf2f(h0)), g1 = f2bf(v.y - bf2f(h1));
                int idx = (n >> 4) * 512 + ((n & 15) + ((kp >> 2) << 4)) * 8 + (kp & 3) * 2;
                *(ushort2*)&bH[idx] = make_ushort2(h0, h1);
                *(ushort2*)&bL[idx] = make_ushort2(g0, g1);
            }
        } else {                                 // n-contiguous (sBn==1)
#pragma unroll
            for (int s = 0; s < 16; ++s) {
                int slot = t + s * 256;
                int n = slot & 127, kk = slot >> 7;
                float v = B[(size_t)(k0 + kk) * sBk + (size_t)(n0 + n)];
                u16 h = f2bf(v);
                int idx = (n >> 4) * 512 + ((n & 15) + ((kk >> 3) << 4)) * 8 + (kk & 7);
                bH[idx] = h;
                bL[idx] = f2bf(v - bf2f(h));
            }
        }
        __syncthreads();

        // ---- compute: per wave 4x4 fragments, 3 MFMAs per fragment pair ----
        short8 vbh[4], vbl[4];
#pragma unroll
        for (int j = 0; j < 4; ++j) {
            int f = wc * 4 + j;
            vbh[j] = *(const short8*)&bH[f * 512 + l * 8];
            vbl[j] = *(const short8*)&bL[f * 512 + l * 8];
        }
#pragma unroll
        for (int i = 0; i < 4; ++i) {
            int f = wr * 4 + i;
            short8 ah = *(const short8*)&aH[f * 512 + l * 8];
            short8 al = *(const short8*)&aL[f * 512 + l * 8];
#pragma unroll
            for (int j = 0; j < 4; ++j) {
                acc[i][j] = __builtin_amdgcn_mfma_f32_16x16x32_bf16(ah, vbh[j], acc[i][j], 0, 0, 0);
                acc[i][j] = __builtin_amdgcn_mfma_f32_16x16x32_bf16(ah, vbl[j], acc[i][j], 0, 0, 0);
                acc[i][j] = __builtin_amdgcn_mfma_f32_16x16x32_bf16(al, vbh[j], acc[i][j], 0, 0, 0);
            }
        }
        __syncthreads();
    }

    // ---- epilogue: C/D mapping col=lane&15, row=(lane>>4)*4+reg ----
    const int col_l = l & 15, row_g = l >> 4;
#pragma unroll
    for (int i = 0; i < 4; ++i) {
        int row_base = m0 + (wr * 4 + i) * 16 + row_g * 4;
#pragma unroll
        for (int j = 0; j < 4; ++j) {
            int col = n0 + (wc * 4 + j) * 16 + col_l;
#pragma unroll
            for (int r = 0; r < 4; ++r) {
                int row = row_base + r;
                float v = acc[i][j][r];
                if (addmat) v += addmat[(size_t)row * ldadd + col];
                if (bias)   v += bias[col];
                if (do_relu) v = fmaxf(v, 0.f);
                Cz[(size_t)row * ldc + col] = v;
            }
        }
    }
}

// C[i] = sum_{s<S} P[s*MN + i], then optional +bias[col] and relu. float4 per thread.
// MN and N multiples of 4; N power of two.
__global__ __launch_bounds__(256)
void reduce_splitk(const float* __restrict__ P, float* __restrict__ C,
                   int S, size_t MN, const float* __restrict__ bias, int N, int do_relu)
{
    size_t base = ((size_t)blockIdx.x * 256 + threadIdx.x) * 4;
    if (base >= MN) return;
    float4 acc = *(const float4*)(P + base);
    for (int s = 1; s < S; ++s) {
        float4 v = *(const float4*)(P + (size_t)s * MN + base);
        acc.x += v.x; acc.y += v.y; acc.z += v.z; acc.w += v.w;
    }
    if (bias) {
        int col = (int)(base & (size_t)(N - 1));
        acc.x += bias[col]; acc.y += bias[col + 1]; acc.z += bias[col + 2]; acc.w += bias[col + 3];
    }
    if (do_relu) {
        acc.x = fmaxf(acc.x, 0.f); acc.y = fmaxf(acc.y, 0.f);
        acc.z = fmaxf(acc.z, 0.f); acc.w = fmaxf(acc.w, 0.f);
    }
    *(float4*)(C + base) = acc;
}

// partial column squared norms: out[z*Ncol + i] = sum_{d in [z*dper,(z+1)*dper)} U[d*Ncol+i]^2
__global__ void colsq_part_kernel(const float* __restrict__ U, float* __restrict__ out,
                                  int Ncol, int dper)
{
    int i = blockIdx.x * blockDim.x + threadIdx.x;
    int z = blockIdx.y;
    if (i >= Ncol) return;
    int d0 = z * dper;
    float s = 0.f;
    for (int d = d0; d < d0 + dper; ++d) { float v = U[(size_t)d * Ncol + i]; s += v * v; }
    out[(size_t)z * Ncol + i] = s;
}

// l[i] = sqrt(ne[i]) / sqrt(sum_d m[i,d]^2); one wave per row
__global__ void lscale_kernel(const float* __restrict__ m, const float* __restrict__ ne,
                              float* __restrict__ l, int rows, int D)
{
    int gid  = blockIdx.x * blockDim.x + threadIdx.x;
    int wave = gid >> 6;
    int lane = gid & 63;
    if (wave >= rows) return;
    const float* r = m + (size_t)wave * D;
    float s = 0.f;
    for (int d = lane; d < D; d += 64) { float v = r[d]; s += v * v; }
#pragma unroll
    for (int off = 32; off; off >>= 1) s += __shfl_down(s, off);
    if (lane == 0) l[wave] = sqrtf(ne[wave]) / sqrtf(s);
}

// f[i*D+d] = U[d*Ncol+i] + l[i]*m[i*D+d]
__global__ void fbuild_kernel(const float* __restrict__ U, const float* __restrict__ m,
                              const float* __restrict__ l, float* __restrict__ f,
                              int rows, int D, int Ncol)
{
    int idx = blockIdx.x * blockDim.x + threadIdx.x;
    if (idx >= rows * D) return;
    int i = idx / D, d = idx - i * D;
    f[idx] = U[(size_t)d * Ncol + i] + l[i] * m[idx];
}

// row-wise L2 normalize in place: e /= max(||e||, 1e-12); one wave per row
__global__ void normrows_kernel(float* __restrict__ E, int rows, int D)
{
    int gid  = blockIdx.x * blockDim.x + threadIdx.x;
    int wave = gid >> 6;
    int lane = gid & 63;
    if (wave >= rows) return;
    float* r = E + (size_t)wave * D;
    float s = 0.f;
    for (int d = lane; d < D; d += 64) { float v = r[d]; s += v * v; }
#pragma unroll
    for (int off = 32; off; off >>= 1) s += __shfl_xor(s, off);
    float denom = fmaxf(sqrtf(s), 1e-12f);
    for (int d = lane; d < D; d += 64) r[d] = r[d] / denom;
}

// per row a of sim (A x A): dd = (2-2*s)^2 ; rowmax(dd), stable top-2 (value,index)
__global__ __launch_bounds__(256)
void rowscan_kernel(const float* __restrict__ sim, float* __restrict__ rowmax,
                    int* __restrict__ n0, int* __restrict__ n1, int A)
{
    int a = blockIdx.x;
    const float* row = sim + (size_t)a * A;
    int tid = threadIdx.x;
    float vmax = -1e30f;
    float b0v = 1e30f, b1v = 1e30f;
    int   b0i = INT_MAX, b1i = INT_MAX;
    for (int j = tid; j < A; j += 256) {
        float s  = row[j];
        float tt = 2.f - 2.f * s;
        float dd = tt * tt;
        vmax = fmaxf(vmax, dd);
        if (dd < b0v) { b1v = b0v; b1i = b0i; b0v = dd; b0i = j; }
        else if (dd < b1v) { b1v = dd; b1i = j; }
    }
    __shared__ float s_max[256], s_v0[256], s_v1[256];
    __shared__ int   s_i0[256], s_i1[256];
    s_max[tid] = vmax; s_v0[tid] = b0v; s_i0[tid] = b0i; s_v1[tid] = b1v; s_i1[tid] = b1i;
    __syncthreads();
    for (int off = 128; off; off >>= 1) {
        if (tid < off) {
            s_max[tid] = fmaxf(s_max[tid], s_max[tid + off]);
            float a0v = s_v0[tid], a1v = s_v1[tid];
            int   a0i = s_i0[tid], a1i = s_i1[tid];
            float c0v = s_v0[tid + off], c1v = s_v1[tid + off];
            int   c0i = s_i0[tid + off], c1i = s_i1[tid + off];
            float r0v, r1v; int r0i, r1i;
            bool c0_lt_a0 = (c0v < a0v) || (c0v == a0v && c0i < a0i);
            if (c0_lt_a0) {
                r0v = c0v; r0i = c0i;
                bool a0_lt_c1 = (a0v < c1v) || (a0v == c1v && a0i < c1i);
                if (a0_lt_c1) { r1v = a0v; r1i = a0i; } else { r1v = c1v; r1i = c1i; }
            } else {
                r0v = a0v; r0i = a0i;
                bool c0_lt_a1 = (c0v < a1v) || (c0v == a1v && c0i < a1i);
                if (c0_lt_a1) { r1v = c0v; r1i = c0i; } else { r1v = a1v; r1i = a1i; }
            }
            s_v0[tid] = r0v; s_i0[tid] = r0i; s_v1[tid] = r1v; s_i1[tid] = r1i;
        }
        __syncthreads();
    }
    if (tid == 0) { rowmax[a] = s_max[0]; n0[a] = s_i0[0]; n1[a] = s_i1[0]; }
}

// per-row k-reciprocal expansion set (k1=1): idx4, vals
__global__ void setbuild_kernel(const float* __restrict__ sim, const float* __restrict__ rmx,
                                const int* __restrict__ n0, const int* __restrict__ n1,
                                int* __restrict__ idx4, float* __restrict__ vals, int A)
{
    int a = blockIdx.x * blockDim.x + threadIdx.x;
    if (a >= A) return;
    int c0 = n0[a], c1 = n1[a];
    bool v0 = (n0[c0] == a) || (n1[c0] == a);
    bool v1 = (n0[c1] == a) || (n1[c1] == a);
    int e0 = n0[c0], e1 = n0[c1];
    bool inR_e0 = (v0 && e0 == c0) || (v1 && e0 == c1);
    bool inR_e1 = (v0 && e1 == c0) || (v1 && e1 == c1);
    bool v2 = v0 && (n0[e0] == c0) && inR_e0;
    bool v3 = v1 && (n0[e1] == c1) && inR_e1;
    int  id[4]  = { c0, c1, e0, e1 };
    bool raw[4] = { v0, v1, v2, v3 };
    bool kept[4];
    kept[0] = raw[0];
#pragma unroll
    for (int j = 1; j < 4; ++j) {
        bool dup = false;
        for (int k = 0; k < j; ++k) dup = dup || (kept[k] && id[k] == id[j]);
        kept[j] = raw[j] && !dup;
    }
    float rm = rmx[a];
    const float* row = sim + (size_t)a * A;
    float wv[4]; float wsum = 0.f;
#pragma unroll
    for (int k = 0; k < 4; ++k) {
        float s  = row[id[k]];
        float tt = 2.f - 2.f * s;
        float dd = tt * tt / rm;
        wv[k] = kept[k] ? expf(-dd) : 0.f;
        wsum += wv[k];
    }
    float den = (wsum > 0.f) ? wsum : 1.f;
#pragma unroll
    for (int k = 0; k < 4; ++k) {
        idx4[a * 4 + k] = id[k];
        vals[a * 4 + k] = wv[k] / den;
    }
}

// outputs: Mp_before, Mp = 1 - (0.7*jac + 0.3*d), thr_flag
__global__ __launch_bounds__(256)
void final_kernel(const float* __restrict__ sim, const float* __restrict__ rmx,
                  const int* __restrict__ idx4, const float* __restrict__ vals,
                  const float* __restrict__ iou, const float* __restrict__ kf,
                  const float* __restrict__ thr, float* __restrict__ out,
                  int Q, int G, int A)
{
    int j = blockIdx.x * 16 + threadIdx.x;
    int i = blockIdx.y * 16 + threadIdx.y;
    if (i >= Q || j >= G) return;
    int b = Q + j;
    float s = sim[(size_t)i * A + b];   // Mp_before[i][j]
    int   ia[4], ib[4];
    float va[4], vb[4];
#pragma unroll
    for (int k = 0; k < 4; ++k) {
        ia[k] = idx4[i * 4 + k]; va[k] = vals[i * 4 + k];
        ib[k] = idx4[b * 4 + k]; vb[k] = vals[b * 4 + k];
    }
    float tt0 = 0.f;
#pragma unroll
    for (int k = 0; k < 4; ++k) {
        float sm = 0.f;
#pragma unroll
        for (int m = 0; m < 4; ++m) sm += (ib[m] == ia[k]) ? vb[m] : 0.f;
        tt0 += fminf(va[k], sm);
    }
    float jac = 1.f - tt0 / (2.f - tt0);
    float tt  = 2.f - 2.f * s;
    float dqg = tt * tt / rmx[i];
    float fin = jac * 0.7f + dqg * 0.3f;
    size_t o  = (size_t)i * G + j;
    size_t QG = (size_t)Q * G;
    out[o]          = s;
    out[QG + o]     = 1.f - fin;
    float iv = iou[o], kv = kf[o];
    out[2 * QG + o] = (kv == -1.f || iv == 0.f || s < thr[0]) ? 1.f : 0.f;
}

extern "C" void kernel_launch(void* const* d_in, const int* in_sizes, int n_in,
                              void* d_out, int out_size, void* d_ws, size_t ws_size,
                              hipStream_t stream)
{
    const float* Us   = (const float*)d_in[0];  // (512, 2048)
    const float* Ut   = (const float*)d_in[1];  // (512, 2048)
    const float* iou  = (const float*)d_in[2];  // (2048, 2048)
    const float* kf   = (const float*)d_in[3];  // (2048, 2048)
    const float* thr  = (const float*)d_in[4];  // (1,)
    const float* W    = (const float*)d_in[5];  // (512, 512)
    const float* bias = (const float*)d_in[6];  // (512,)
    float* out = (float*)d_out;

    const int Q = 2048, G = 2048, D = 512, A = 4096;
    const size_t M1 = 1024 * 1024;
    const size_t MN = (size_t)Q * D;            // 1M floats (2048x512 outputs)

    float* ws  = (float*)d_ws;
    // Aliased layout (peak ~72.5 MB):
    float* sim = ws;             // 16M floats; written at G6 (early bufs dead by then)
    float* E   = ws + 16 * M1;   // 2M floats (e1 rows 0..2047, e2 rows 2048..4095)
    float* Mp0 = ws;             // 4M floats (dead before sim written)
    float* m1  = ws + 4 * M1;    // 1M
    float* m2  = ws + 5 * M1;    // 1M
    float* f1  = ws + 6 * M1;    // 1M
    float* f2  = ws + 7 * M1;    // 1M
    float* Pk  = ws + 8 * M1;    // split-K partials: up to 8M floats [8M1,16M1), free here
    float* ne  = ws + 18 * M1;   // 4096 (ne1) + 4096 (ne2)
    float* lv  = ne + 2 * 4096;  // 4096 (l1) + 4096 (l2)
    float* rmx = lv + 2 * 4096;  // 4096
    int*   n0v = (int*)(rmx + 4096);
    int*   n1v = n0v + 4096;
    int*   id4 = n1v + 4096;     // 4*4096
    float* vls = (float*)(id4 + 4 * 4096); // 4*4096

    // G1: Mp0 = Us^T Ut + iou   (M=2048,N=2048,K=512)  A(m,k)=Us[k*2048+m], B(k,n)=Ut[k*2048+n]
    gemm_mfma<<<dim3(Q / BM, G / BN, 1), 256, 0, stream>>>(
        Us, Ut, Mp0, D, D, 0, 1, 2048, 2048, 1, 2048, iou, 2048, nullptr, 0);

    // G2: m1 = Mp0 * Ut^T  (M=2048,N=512,K=2048), split-K 8 -> 512 blocks
    gemm_mfma<<<dim3(Q / BM, D / BN, 8), 256, 0, stream>>>(
        Mp0, Ut, Pk, Q, Q / 8, MN, 2048, 1, 1, 2048, 512, nullptr, 0, nullptr, 0);
    reduce_splitk<<<(int)(MN / 1024), 256, 0, stream>>>(Pk, m1, 8, MN, nullptr, D, 0);
    // G3: m2 = Mp0^T * Us^T  (M=2048,N=512,K=2048), split-K 8
    gemm_mfma<<<dim3(Q / BM, D / BN, 8), 256, 0, stream>>>(
        Mp0, Us, Pk, Q, Q / 8, MN, 1, 2048, 1, 2048, 512, nullptr, 0, nullptr, 0);
    reduce_splitk<<<(int)(MN / 1024), 256, 0, stream>>>(Pk, m2, 8, MN, nullptr, D, 0);

    // colsq via 16-slice partials into Pk (free until G4), then reduce
    colsq_part_kernel<<<dim3(Q / 256, 16), 256, 0, stream>>>(Us, Pk, Q, D / 16);
    reduce_splitk<<<2, 256, 0, stream>>>(Pk, ne, 16, (size_t)Q, nullptr, 4, 0);
    colsq_part_kernel<<<dim3(G / 256, 16), 256, 0, stream>>>(Ut, Pk, G, D / 16);
    reduce_splitk<<<2, 256, 0, stream>>>(Pk, ne + 2048, 16, (size_t)G, nullptr, 4, 0);

    lscale_kernel<<<(Q * 64) / 256, 256, 0, stream>>>(m1, ne, lv, Q, D);
    lscale_kernel<<<(G * 64) / 256, 256, 0, stream>>>(m2, ne + 2048, lv + 2048, G, D);
    fbuild_kernel<<<(Q * D) / 256, 256, 0, stream>>>(Us, m1, lv, f1, Q, D, Q);
    fbuild_kernel<<<(G * D) / 256, 256, 0, stream>>>(Ut, m2, lv + 2048, f2, G, D, G);

    // G4/G5: e = relu(f * W^T + b) -> E  (M=2048,N=512,K=512), split-K 4 -> 256 blocks
    gemm_mfma<<<dim3(Q / BM, D / BN, 4), 256, 0, stream>>>(
        f1, W, Pk, D, D / 4, MN, 512, 1, 1, 512, 512, nullptr, 0, nullptr, 0);
    reduce_splitk<<<(int)(MN / 1024), 256, 0, stream>>>(Pk, E, 4, MN, bias, D, 1);
    gemm_mfma<<<dim3(G / BM, D / BN, 4), 256, 0, stream>>>(
        f2, W, Pk, D, D / 4, MN, 512, 1, 1, 512, 512, nullptr, 0, nullptr, 0);
    reduce_splitk<<<(int)(MN / 1024), 256, 0, stream>>>(Pk, E + (size_t)Q * D, 4, MN, bias, D, 1);

    normrows_kernel<<<(A * 64) / 256, 256, 0, stream>>>(E, A, D);

    // G6: sim = E E^T  (M=N=4096,K=512)  A(m,k)=E[m*512+k], B(k,n)=E[n*512+k]
    gemm_mfma<<<dim3(A / BM, A / BN, 1), 256, 0, stream>>>(
        E, E, sim, D, D, 0, 512, 1, 1, 512, 4096, nullptr, 0, nullptr, 0);

    rowscan_kernel<<<A, 256, 0, stream>>>(sim, rmx, n0v, n1v, A);
    setbuild_kernel<<<A / 256, 256, 0, stream>>>(sim, rmx, n0v, n1v, id4, vls, A);
    final_kernel<<<dim3(G / 16, Q / 16), dim3(16, 16), 0, stream>>>(
        sim, rmx, id4, vls, iou, kf, thr, out, Q, G, A);
}